// Round 2
// baseline (1385.116 us; speedup 1.0000x reference)
//
#include <hip/hip_runtime.h>

#define NE 800000
#define NN 50000
#define HD 128
#define FFD 512

typedef __bf16 bf16;
typedef bf16 bf16x8 __attribute__((ext_vector_type(8)));
typedef float f32x4 __attribute__((ext_vector_type(4)));

__device__ __forceinline__ float gelu_f(float x) {
    return 0.5f * x * (1.0f + erff(x * 0.70710678118654752f));
}

__device__ __forceinline__ bf16x8 cvt8(f32x4 a, f32x4 b) {
    bf16x8 t;
    t[0] = (bf16)a[0]; t[1] = (bf16)a[1]; t[2] = (bf16)a[2]; t[3] = (bf16)a[3];
    t[4] = (bf16)b[0]; t[5] = (bf16)b[1]; t[6] = (bf16)b[2]; t[7] = (bf16)b[3];
    return t;
}

// ---- weight fp32 -> bf16 pre-convert (once per call, into ws) ----
__global__ void cvt_weights(const float* __restrict__ W1, const float* __restrict__ W2,
                            const float* __restrict__ W3, const float* __restrict__ Win,
                            const float* __restrict__ Wout, bf16* __restrict__ o) {
    int i = blockIdx.x * 256 + threadIdx.x;
    if (i < 49152)        o[i] = (bf16)W1[i];
    else if (i < 65536)   o[i] = (bf16)W2[i - 49152];
    else if (i < 81920)   o[i] = (bf16)W3[i - 65536];
    else if (i < 147456)  o[i] = (bf16)Win[i - 81920];
    else if (i < 212992)  o[i] = (bf16)Wout[i - 147456];
}

__global__ void hist_kernel(const int* __restrict__ src, int* __restrict__ cnt) {
    int i = blockIdx.x * 256 + threadIdx.x;
    if (i < NE) atomicAdd(cnt + src[i], 1);
}

// ---- single-block exclusive scan of cnt[NN] -> head[NN] (counting-sort offsets) ----
__global__ __launch_bounds__(1024) void scan_kernel(const int* __restrict__ cnt,
                                                    int* __restrict__ head) {
    __shared__ int wsum[16];
    __shared__ int carry;
    const int tid = threadIdx.x, lane = tid & 63, w = tid >> 6;
    if (tid == 0) carry = 0;
    __syncthreads();
    for (int base = 0; base < NN; base += 1024) {
        int i = base + tid;
        int v = (i < NN) ? cnt[i] : 0;
        int x = v;
#pragma unroll
        for (int m = 1; m < 64; m <<= 1) {
            int y = __shfl_up(x, m, 64);
            if (lane >= m) x += y;
        }
        if (lane == 63) wsum[w] = x;
        __syncthreads();
        if (w == 0) {
            int s = (lane < 16) ? wsum[lane] : 0;
#pragma unroll
            for (int m = 1; m < 16; m <<= 1) {
                int y = __shfl_up(s, m, 64);
                if (lane >= m) s += y;
            }
            if (lane < 16) wsum[lane] = s;
        }
        __syncthreads();
        int excl = carry + (w > 0 ? wsum[w - 1] : 0) + x - v;
        if (i < NN) head[i] = excl;
        int total = wsum[15];
        __syncthreads();
        if (tid == 0) carry += total;
        __syncthreads();
    }
}

// ---- counting-sort placement: perm = edge ids ordered by src ----
__global__ void scatter_perm(const int* __restrict__ src, int* __restrict__ head,
                             int* __restrict__ perm) {
    int i = blockIdx.x * 256 + threadIdx.x;
    if (i < NE) {
        int pos = atomicAdd(head + src[i], 1);
        perm[pos] = i;
    }
}

// ---- edge MLP over src-sorted edges + segmented scatter-reduce ----
// block = 256 thr (4 waves, 2x2 wave grid), tile = 128 edges x 128 cols.
__global__ __launch_bounds__(256, 2) void edge_mlp(
    const float* __restrict__ hV, const float* __restrict__ hE,
    const int* __restrict__ src, const int* __restrict__ dst,
    const int* __restrict__ perm,
    const bf16* __restrict__ W1b, const bf16* __restrict__ W2b, const bf16* __restrict__ W3b,
    const float* __restrict__ b1, const float* __restrict__ b2, const float* __restrict__ b3,
    float* __restrict__ segsum)
{
    // union: bf16 activations (128x136 = 34816 B) / fp32 messages (128x132 = 67584 B)
    __shared__ __align__(16) char smem[128 * 132 * 4];
    bf16  (*lx)[136] = (bf16 (*)[136])smem;
    float (*lz)[132] = (float (*)[132])smem;
    __shared__ int ssrc[128];

    const int tid  = threadIdx.x;
    const int wave = tid >> 6, lane = tid & 63;
    const int wr = wave >> 1, wc = wave & 1;
    const int quad = lane >> 4, l16 = lane & 15;
    const int row0 = blockIdx.x * 128;

    if (tid < 128) ssrc[tid] = src[perm[row0 + tid]];

    int arow[4], asrc[4], adst[4];
#pragma unroll
    for (int rt = 0; rt < 4; ++rt) {
        int e = perm[row0 + wr * 64 + rt * 16 + l16];
        arow[rt] = e; asrc[rt] = src[e]; adst[rt] = dst[e];
    }

    f32x4 acc[4][4];
#pragma unroll
    for (int i = 0; i < 4; ++i)
#pragma unroll
        for (int j = 0; j < 4; ++j) acc[i][j] = (f32x4){0.f, 0.f, 0.f, 0.f};

    // ---- layer 1: K = 384 = [hV[src] | hE | hV[dst]] ----
#pragma unroll
    for (int ks = 0; ks < 12; ++ks) {
        const int k = ks * 32 + quad * 8;
        bf16x8 a[4];
#pragma unroll
        for (int rt = 0; rt < 4; ++rt) {
            const float* p;
            if (ks < 4)      p = hV + (size_t)asrc[rt] * HD + k;
            else if (ks < 8) p = hE + (size_t)arow[rt] * HD + (k - 128);
            else             p = hV + (size_t)adst[rt] * HD + (k - 256);
            f32x4 f0 = *(const f32x4*)p;
            f32x4 f1 = *(const f32x4*)(p + 4);
            a[rt] = cvt8(f0, f1);
        }
        bf16x8 b[4];
#pragma unroll
        for (int ct = 0; ct < 4; ++ct) {
            int col = wc * 64 + ct * 16 + l16;
            b[ct] = *(const bf16x8*)(W1b + (size_t)col * 384 + ks * 32 + quad * 8);
        }
#pragma unroll
        for (int rt = 0; rt < 4; ++rt)
#pragma unroll
            for (int ct = 0; ct < 4; ++ct)
                acc[rt][ct] = __builtin_amdgcn_mfma_f32_16x16x32_bf16(a[rt], b[ct], acc[rt][ct], 0, 0, 0);
    }

    // epilogue 1 -> lx (gelu, bf16). C/D layout: col=lane&15, row=quad*4+reg.
#pragma unroll
    for (int ct = 0; ct < 4; ++ct) {
        int col = wc * 64 + ct * 16 + l16;
        float bias = b1[col];
#pragma unroll
        for (int rt = 0; rt < 4; ++rt)
#pragma unroll
            for (int r = 0; r < 4; ++r)
                lx[wr * 64 + rt * 16 + quad * 4 + r][col] = (bf16)gelu_f(acc[rt][ct][r] + bias);
    }
    __syncthreads();

    // ---- layer 2: K = 128 ----
#pragma unroll
    for (int i = 0; i < 4; ++i)
#pragma unroll
        for (int j = 0; j < 4; ++j) acc[i][j] = (f32x4){0.f, 0.f, 0.f, 0.f};
#pragma unroll
    for (int ks = 0; ks < 4; ++ks) {
        bf16x8 a[4], b[4];
#pragma unroll
        for (int rt = 0; rt < 4; ++rt)
            a[rt] = *(const bf16x8*)&lx[wr * 64 + rt * 16 + l16][ks * 32 + quad * 8];
#pragma unroll
        for (int ct = 0; ct < 4; ++ct)
            b[ct] = *(const bf16x8*)(W2b + (size_t)(wc * 64 + ct * 16 + l16) * HD + ks * 32 + quad * 8);
#pragma unroll
        for (int rt = 0; rt < 4; ++rt)
#pragma unroll
            for (int ct = 0; ct < 4; ++ct)
                acc[rt][ct] = __builtin_amdgcn_mfma_f32_16x16x32_bf16(a[rt], b[ct], acc[rt][ct], 0, 0, 0);
    }
    __syncthreads();

    // epilogue 2 -> lx (gelu, bf16)
#pragma unroll
    for (int ct = 0; ct < 4; ++ct) {
        int col = wc * 64 + ct * 16 + l16;
        float bias = b2[col];
#pragma unroll
        for (int rt = 0; rt < 4; ++rt)
#pragma unroll
            for (int r = 0; r < 4; ++r)
                lx[wr * 64 + rt * 16 + quad * 4 + r][col] = (bf16)gelu_f(acc[rt][ct][r] + bias);
    }
    __syncthreads();

    // ---- layer 3: K = 128 ----
#pragma unroll
    for (int i = 0; i < 4; ++i)
#pragma unroll
        for (int j = 0; j < 4; ++j) acc[i][j] = (f32x4){0.f, 0.f, 0.f, 0.f};
#pragma unroll
    for (int ks = 0; ks < 4; ++ks) {
        bf16x8 a[4], b[4];
#pragma unroll
        for (int rt = 0; rt < 4; ++rt)
            a[rt] = *(const bf16x8*)&lx[wr * 64 + rt * 16 + l16][ks * 32 + quad * 8];
#pragma unroll
        for (int ct = 0; ct < 4; ++ct)
            b[ct] = *(const bf16x8*)(W3b + (size_t)(wc * 64 + ct * 16 + l16) * HD + ks * 32 + quad * 8);
#pragma unroll
        for (int rt = 0; rt < 4; ++rt)
#pragma unroll
            for (int ct = 0; ct < 4; ++ct)
                acc[rt][ct] = __builtin_amdgcn_mfma_f32_16x16x32_bf16(a[rt], b[ct], acc[rt][ct], 0, 0, 0);
    }
    __syncthreads();   // all waves done reading lx before overwriting as lz

    // epilogue 3: z = acc + b3 -> lz (fp32)
    float b3c[4];
#pragma unroll
    for (int ct = 0; ct < 4; ++ct) b3c[ct] = b3[wc * 64 + ct * 16 + l16];
#pragma unroll
    for (int ct = 0; ct < 4; ++ct)
#pragma unroll
        for (int rt = 0; rt < 4; ++rt)
#pragma unroll
            for (int r = 0; r < 4; ++r)
                lz[wr * 64 + rt * 16 + quad * 4 + r][wc * 64 + ct * 16 + l16] =
                    acc[rt][ct][r] + b3c[ct];
    __syncthreads();

    // segmented reduce: edges sorted by src -> runs of equal src are contiguous rows.
    // thread t: col = t&127, rows [h*64, h*64+64). wave-uniform branches (same rows/lane).
    {
        const int c = tid & 127, h = tid >> 7;
        const int rbeg = h * 64, rend = rbeg + 64;
        float sum = lz[rbeg][c];
        int cur = ssrc[rbeg];
        for (int r = rbeg + 1; r < rend; ++r) {
            int s = ssrc[r];
            float v = lz[r][c];
            if (s != cur) {
                atomicAdd(segsum + (size_t)cur * HD + c, sum);
                cur = s; sum = v;
            } else {
                sum += v;
            }
        }
        atomicAdd(segsum + (size_t)cur * HD + c, sum);
    }
}

// ---- node: dh + residual + LN1 -> FFN (MFMA, FF in 64-col chunks) -> residual + LN2 ----
__global__ __launch_bounds__(256, 2) void node_ffn(
    const float* __restrict__ hV, float* __restrict__ out /* segsum in, h_V out */,
    const int* __restrict__ cnt,
    const bf16* __restrict__ Winb, const bf16* __restrict__ Woutb,
    const float* __restrict__ bin, const float* __restrict__ bout,
    const float* __restrict__ g1, const float* __restrict__ be1,
    const float* __restrict__ g2, const float* __restrict__ be2)
{
    __shared__ bf16 lx[128][136];     // LN1 output x (persists; also residual for LN2)
    __shared__ bf16 ly[128][72];      // gelu(x@Win.T) 64-col chunk
    __shared__ float ps[128][2], pq[128][2];
    const int tid  = threadIdx.x;
    const int wave = tid >> 6, lane = tid & 63;
    const int wr = wave >> 1, wc = wave & 1;
    const int quad = lane >> 4, l16 = lane & 15;
    const int base = blockIdx.x * 128;

    // phase 1: u = hV + segsum/max(cnt,1)/30 ; LN1 -> lx (bf16). one row per wave-iter.
    for (int r = 0; r < 32; ++r) {
        int rl = wave * 32 + r;
        int node = base + rl;
        float u0 = 0.f, u1 = 0.f;
        bool valid = node < NN;
        if (valid) {
            int c = cnt[node];
            float inv = 1.0f / (30.0f * (float)(c > 1 ? c : 1));
            const float2 h = *(const float2*)(hV  + (size_t)node * HD + 2 * lane);
            const float2 s = *(const float2*)(out + (size_t)node * HD + 2 * lane);
            u0 = h.x + s.x * inv;
            u1 = h.y + s.y * inv;
        }
        float sm = u0 + u1, sq = u0 * u0 + u1 * u1;
#pragma unroll
        for (int m = 1; m < 64; m <<= 1) {
            sm += __shfl_xor(sm, m, 64);
            sq += __shfl_xor(sq, m, 64);
        }
        float mean = sm * (1.0f / 128.0f);
        float var  = sq * (1.0f / 128.0f) - mean * mean;
        float rstd = rsqrtf(var + 1e-5f);
        int c0 = 2 * lane;
        float x0 = valid ? ((u0 - mean) * rstd * g1[c0]     + be1[c0])     : 0.f;
        float x1 = valid ? ((u1 - mean) * rstd * g1[c0 + 1] + be1[c0 + 1]) : 0.f;
        lx[rl][c0] = (bf16)x0; lx[rl][c0 + 1] = (bf16)x1;
    }
    __syncthreads();

    f32x4 oacc[4][4];
#pragma unroll
    for (int i = 0; i < 4; ++i)
#pragma unroll
        for (int j = 0; j < 4; ++j) oacc[i][j] = (f32x4){0.f, 0.f, 0.f, 0.f};

    for (int c = 0; c < 8; ++c) {   // FF=512 in 8 chunks of 64
        f32x4 a1[4][2];
#pragma unroll
        for (int i = 0; i < 4; ++i)
#pragma unroll
            for (int j = 0; j < 2; ++j) a1[i][j] = (f32x4){0.f, 0.f, 0.f, 0.f};
#pragma unroll
        for (int ks = 0; ks < 4; ++ks) {
            bf16x8 a[4], b[2];
#pragma unroll
            for (int rt = 0; rt < 4; ++rt)
                a[rt] = *(const bf16x8*)&lx[wr * 64 + rt * 16 + l16][ks * 32 + quad * 8];
#pragma unroll
            for (int ct = 0; ct < 2; ++ct) {
                int f = c * 64 + wc * 32 + ct * 16 + l16;
                b[ct] = *(const bf16x8*)(Winb + (size_t)f * HD + ks * 32 + quad * 8);
            }
#pragma unroll
            for (int rt = 0; rt < 4; ++rt)
#pragma unroll
                for (int ct = 0; ct < 2; ++ct)
                    a1[rt][ct] = __builtin_amdgcn_mfma_f32_16x16x32_bf16(a[rt], b[ct], a1[rt][ct], 0, 0, 0);
        }
        __syncthreads();
#pragma unroll
        for (int ct = 0; ct < 2; ++ct) {
            int f  = c * 64 + wc * 32 + ct * 16 + l16;
            int fl = wc * 32 + ct * 16 + l16;
            float bias = bin[f];
#pragma unroll
            for (int rt = 0; rt < 4; ++rt)
#pragma unroll
                for (int r = 0; r < 4; ++r)
                    ly[wr * 64 + rt * 16 + quad * 4 + r][fl] = (bf16)gelu_f(a1[rt][ct][r] + bias);
        }
        __syncthreads();
#pragma unroll
        for (int ks = 0; ks < 2; ++ks) {
            bf16x8 a[4], b[4];
#pragma unroll
            for (int rt = 0; rt < 4; ++rt)
                a[rt] = *(const bf16x8*)&ly[wr * 64 + rt * 16 + l16][ks * 32 + quad * 8];
#pragma unroll
            for (int ct = 0; ct < 4; ++ct) {
                int o = wc * 64 + ct * 16 + l16;
                b[ct] = *(const bf16x8*)(Woutb + (size_t)o * FFD + c * 64 + ks * 32 + quad * 8);
            }
#pragma unroll
            for (int rt = 0; rt < 4; ++rt)
#pragma unroll
                for (int ct = 0; ct < 4; ++ct)
                    oacc[rt][ct] = __builtin_amdgcn_mfma_f32_16x16x32_bf16(a[rt], b[ct], oacc[rt][ct], 0, 0, 0);
        }
    }

    // z = ffn + b_out + x (residual); LN2 row stats via quad butterfly + LDS combine
    float bo[4];
#pragma unroll
    for (int ct = 0; ct < 4; ++ct) bo[ct] = bout[wc * 64 + ct * 16 + l16];
#pragma unroll
    for (int rt = 0; rt < 4; ++rt)
#pragma unroll
        for (int r = 0; r < 4; ++r) {
            int rl = wr * 64 + rt * 16 + quad * 4 + r;
            float sm = 0.f, sq = 0.f;
#pragma unroll
            for (int ct = 0; ct < 4; ++ct) {
                int o = wc * 64 + ct * 16 + l16;
                float zz = oacc[rt][ct][r] + bo[ct] + (float)lx[rl][o];
                oacc[rt][ct][r] = zz;
                sm += zz; sq += zz * zz;
            }
#pragma unroll
            for (int m = 1; m < 16; m <<= 1) {
                sm += __shfl_xor(sm, m, 64);
                sq += __shfl_xor(sq, m, 64);
            }
            if (l16 == 0) { ps[rl][wc] = sm; pq[rl][wc] = sq; }
        }
    __syncthreads();
#pragma unroll
    for (int rt = 0; rt < 4; ++rt)
#pragma unroll
        for (int r = 0; r < 4; ++r) {
            int rl = wr * 64 + rt * 16 + quad * 4 + r;
            int node = base + rl;
            float S = ps[rl][0] + ps[rl][1];
            float Q = pq[rl][0] + pq[rl][1];
            float mean = S * (1.0f / 128.0f);
            float var  = Q * (1.0f / 128.0f) - mean * mean;
            float rstd = rsqrtf(var + 1e-5f);
            if (node < NN) {
#pragma unroll
                for (int ct = 0; ct < 4; ++ct) {
                    int o = wc * 64 + ct * 16 + l16;
                    out[(size_t)node * HD + o] = (oacc[rt][ct][r] - mean) * rstd * g2[o] + be2[o];
                }
            }
        }
}

extern "C" void kernel_launch(void* const* d_in, const int* in_sizes, int n_in,
                              void* d_out, int out_size, void* d_ws, size_t ws_size,
                              hipStream_t stream) {
    const float* hV   = (const float*)d_in[0];
    const float* hE   = (const float*)d_in[1];
    const int*   src  = (const int*)d_in[2];
    // d_in[3] batch_id unused
    const int*   dst  = (const int*)d_in[4];
    const float* W1   = (const float*)d_in[5];
    const float* b1   = (const float*)d_in[6];
    const float* W2   = (const float*)d_in[7];
    const float* b2   = (const float*)d_in[8];
    const float* W3   = (const float*)d_in[9];
    const float* b3   = (const float*)d_in[10];
    const float* g1   = (const float*)d_in[11];
    const float* be1  = (const float*)d_in[12];
    const float* g2   = (const float*)d_in[13];
    const float* be2  = (const float*)d_in[14];
    const float* Win  = (const float*)d_in[15];
    const float* bin  = (const float*)d_in[16];
    const float* Wout = (const float*)d_in[17];
    const float* bout = (const float*)d_in[18];

    float* out = (float*)d_out;
    // ws layout (bytes): wbf 0..425984, cnt @425984 (200000), head @625984 (200000),
    //                    perm @825984 (3200000) -> total ~4.03 MB
    bf16* wbf  = (bf16*)d_ws;
    int*  cnt  = (int*)((char*)d_ws + 425984);
    int*  head = (int*)((char*)d_ws + 625984);
    int*  perm = (int*)((char*)d_ws + 825984);

    hipMemsetAsync(d_out, 0, (size_t)NN * HD * sizeof(float), stream);  // seg_sum acc
    hipMemsetAsync(cnt, 0, NN * sizeof(int), stream);

    cvt_weights<<<832, 256, 0, stream>>>(W1, W2, W3, Win, Wout, wbf);
    hist_kernel<<<(NE + 255) / 256, 256, 0, stream>>>(src, cnt);
    scan_kernel<<<1, 1024, 0, stream>>>(cnt, head);
    scatter_perm<<<(NE + 255) / 256, 256, 0, stream>>>(src, head, perm);
    edge_mlp<<<NE / 128, 256, 0, stream>>>(hV, hE, src, dst, perm,
                                           wbf, wbf + 49152, wbf + 65536,
                                           b1, b2, b3, out);
    node_ffn<<<(NN + 127) / 128, 256, 0, stream>>>(hV, out, cnt,
                                                   wbf + 81920, wbf + 147456,
                                                   bin, bout, g1, be1, g2, be2);
}

// Round 3
// 1119.450 us; speedup vs baseline: 1.2373x; 1.2373x over previous
//
#include <hip/hip_runtime.h>

#define NE 800000
#define NN 50000
#define HD 128
#define FFD 512

typedef __bf16 bf16;
typedef bf16 bf16x8 __attribute__((ext_vector_type(8)));
typedef float f32x4 __attribute__((ext_vector_type(4)));

__device__ __forceinline__ float gelu_f(float x) {
    return 0.5f * x * (1.0f + erff(x * 0.70710678118654752f));
}

__device__ __forceinline__ bf16x8 cvt8(f32x4 a, f32x4 b) {
    bf16x8 t;
    t[0] = (bf16)a[0]; t[1] = (bf16)a[1]; t[2] = (bf16)a[2]; t[3] = (bf16)a[3];
    t[4] = (bf16)b[0]; t[5] = (bf16)b[1]; t[6] = (bf16)b[2]; t[7] = (bf16)b[3];
    return t;
}

// ---- weight fp32 -> bf16 pre-convert ----
__global__ void cvt_weights(const float* __restrict__ W1, const float* __restrict__ W2,
                            const float* __restrict__ W3, const float* __restrict__ Win,
                            const float* __restrict__ Wout, bf16* __restrict__ o) {
    int i = blockIdx.x * 256 + threadIdx.x;
    if (i < 49152)        o[i] = (bf16)W1[i];
    else if (i < 65536)   o[i] = (bf16)W2[i - 49152];
    else if (i < 81920)   o[i] = (bf16)W3[i - 65536];
    else if (i < 147456)  o[i] = (bf16)Win[i - 81920];
    else if (i < 212992)  o[i] = (bf16)Wout[i - 147456];
}

__global__ void hist_kernel(const int* __restrict__ src, int* __restrict__ cnt) {
    int i = blockIdx.x * 256 + threadIdx.x;
    if (i < NE) atomicAdd(cnt + src[i], 1);
}

// ---- hierarchical exclusive scan: cnt[NN] -> head[NN] ----
__global__ void scan_a(const int* __restrict__ cnt, int* __restrict__ head,
                       int* __restrict__ bsum) {
    __shared__ int ws[4];
    const int t = threadIdx.x, lane = t & 63, w = t >> 6;
    int i = blockIdx.x * 256 + t;
    int v = (i < NN) ? cnt[i] : 0;
    int x = v;
#pragma unroll
    for (int m = 1; m < 64; m <<= 1) {
        int y = __shfl_up(x, m, 64);
        if (lane >= m) x += y;
    }
    if (lane == 63) ws[w] = x;
    __syncthreads();
    if (t == 0) {
        int s = 0;
#pragma unroll
        for (int j = 0; j < 4; ++j) { int tv = ws[j]; ws[j] = s; s += tv; }
        bsum[blockIdx.x] = s;
    }
    __syncthreads();
    if (i < NN) head[i] = ws[w] + x - v;
}

__global__ void scan_b(int* __restrict__ bsum, int nb) {
    __shared__ int ws[4];
    const int t = threadIdx.x, lane = t & 63, w = t >> 6;
    int v = (t < nb) ? bsum[t] : 0;
    int x = v;
#pragma unroll
    for (int m = 1; m < 64; m <<= 1) {
        int y = __shfl_up(x, m, 64);
        if (lane >= m) x += y;
    }
    if (lane == 63) ws[w] = x;
    __syncthreads();
    if (t == 0) {
        int s = 0;
#pragma unroll
        for (int j = 0; j < 4; ++j) { int tv = ws[j]; ws[j] = s; s += tv; }
    }
    __syncthreads();
    if (t < nb) bsum[t] = ws[w] + x - v;
}

__global__ void scan_c(int* __restrict__ head, const int* __restrict__ bsum) {
    int i = blockIdx.x * 256 + threadIdx.x;
    if (i < NN) head[i] += bsum[blockIdx.x];
}

__global__ void scatter_perm(const int* __restrict__ src, int* __restrict__ head,
                             int* __restrict__ perm) {
    int i = blockIdx.x * 256 + threadIdx.x;
    if (i < NE) {
        int pos = atomicAdd(head + src[i], 1);
        perm[pos] = i;
    }
}

// ---- edge MLP over src-sorted edges: cooperative LDS-staged gather + MFMA ----
// block = 256 thr (4 waves, 2x2), tile = 128 edges x 128 cols.
// LDS: As dbuf 2*9216 + lx/lz 34816 + ssrc 512 = 53760 B -> 3 blocks/CU.
__global__ __launch_bounds__(256, 3) void edge_mlp(
    const float* __restrict__ hV, const float* __restrict__ hE,
    const int* __restrict__ src, const int* __restrict__ dst,
    const int* __restrict__ perm,
    const bf16* __restrict__ W1b, const bf16* __restrict__ W2b, const bf16* __restrict__ W3b,
    const float* __restrict__ b1, const float* __restrict__ b2, const float* __restrict__ b3,
    float* __restrict__ segsum)
{
    __shared__ bf16 As[2][128][36];              // staged A k-chunk, +4 pad (conflict-free b128)
    __shared__ __align__(16) char smem[128 * 136 * 2];
    __shared__ int ssrc[128];
    bf16  (*lx)[136] = (bf16 (*)[136])smem;      // bf16 activations 128x136
    float (*lz)[68]  = (float (*)[68])smem;      // fp32 z half-tile 128x(64+4)

    const int tid  = threadIdx.x;
    const int wave = tid >> 6, lane = tid & 63;
    const int wr = wave >> 1, wc = wave & 1;
    const int quad = lane >> 4, l16 = lane & 15;
    const int row0 = blockIdx.x * 128;

    // staging identity: thread t handles row t>>1, k-half (t&1)*16
    const int myrow = tid >> 1, khalf = (tid & 1) * 16;
    const int me    = perm[row0 + myrow];
    const int mysrc = src[me], mydst = dst[me];
    if ((tid & 1) == 0) ssrc[myrow] = mysrc;

    // prologue: stage ks=0
    {
        const float* p = hV + (size_t)mysrc * HD + khalf;
        f32x4 s0 = *(const f32x4*)p,       s1 = *(const f32x4*)(p + 4);
        f32x4 s2 = *(const f32x4*)(p + 8), s3 = *(const f32x4*)(p + 12);
        *(bf16x8*)&As[0][myrow][khalf]     = cvt8(s0, s1);
        *(bf16x8*)&As[0][myrow][khalf + 8] = cvt8(s2, s3);
    }
    __syncthreads();

    f32x4 acc[4][4];
#pragma unroll
    for (int i = 0; i < 4; ++i)
#pragma unroll
        for (int j = 0; j < 4; ++j) acc[i][j] = (f32x4){0.f, 0.f, 0.f, 0.f};

    // ---- layer 1: K = 384, double-buffered staged gather ----
    for (int ks = 0; ks < 12; ++ks) {
        const int cur = ks & 1, nxt = cur ^ 1;
        const bool more = ks < 11;
        f32x4 s0, s1, s2, s3;
        if (more) {                               // issue next-chunk gather loads NOW
            const int kn = (ks + 1) * 32 + khalf;
            const float* p;
            if (kn < 128)      p = hV + (size_t)mysrc * HD + kn;
            else if (kn < 256) p = hE + (size_t)me    * HD + (kn - 128);
            else               p = hV + (size_t)mydst * HD + (kn - 256);
            s0 = *(const f32x4*)p;       s1 = *(const f32x4*)(p + 4);
            s2 = *(const f32x4*)(p + 8); s3 = *(const f32x4*)(p + 12);
        }
        bf16x8 a[4], b[4];
#pragma unroll
        for (int rt = 0; rt < 4; ++rt)
            a[rt] = *(const bf16x8*)&As[cur][wr * 64 + rt * 16 + l16][quad * 8];
#pragma unroll
        for (int ct = 0; ct < 4; ++ct) {
            int col = wc * 64 + ct * 16 + l16;
            b[ct] = *(const bf16x8*)(W1b + (size_t)col * 384 + ks * 32 + quad * 8);
        }
#pragma unroll
        for (int rt = 0; rt < 4; ++rt)
#pragma unroll
            for (int ct = 0; ct < 4; ++ct)
                acc[rt][ct] = __builtin_amdgcn_mfma_f32_16x16x32_bf16(a[rt], b[ct], acc[rt][ct], 0, 0, 0);
        if (more) {
            *(bf16x8*)&As[nxt][myrow][khalf]     = cvt8(s0, s1);
            *(bf16x8*)&As[nxt][myrow][khalf + 8] = cvt8(s2, s3);
        }
        __syncthreads();
    }

    // epilogue 1 -> lx (gelu, bf16). C/D layout: col=lane&15, row=quad*4+reg.
#pragma unroll
    for (int ct = 0; ct < 4; ++ct) {
        int col = wc * 64 + ct * 16 + l16;
        float bias = b1[col];
#pragma unroll
        for (int rt = 0; rt < 4; ++rt)
#pragma unroll
            for (int r = 0; r < 4; ++r)
                lx[wr * 64 + rt * 16 + quad * 4 + r][col] = (bf16)gelu_f(acc[rt][ct][r] + bias);
    }
    __syncthreads();

    // ---- layer 2: K = 128 ----
#pragma unroll
    for (int i = 0; i < 4; ++i)
#pragma unroll
        for (int j = 0; j < 4; ++j) acc[i][j] = (f32x4){0.f, 0.f, 0.f, 0.f};
#pragma unroll
    for (int ks = 0; ks < 4; ++ks) {
        bf16x8 a[4], b[4];
#pragma unroll
        for (int rt = 0; rt < 4; ++rt)
            a[rt] = *(const bf16x8*)&lx[wr * 64 + rt * 16 + l16][ks * 32 + quad * 8];
#pragma unroll
        for (int ct = 0; ct < 4; ++ct)
            b[ct] = *(const bf16x8*)(W2b + (size_t)(wc * 64 + ct * 16 + l16) * HD + ks * 32 + quad * 8);
#pragma unroll
        for (int rt = 0; rt < 4; ++rt)
#pragma unroll
            for (int ct = 0; ct < 4; ++ct)
                acc[rt][ct] = __builtin_amdgcn_mfma_f32_16x16x32_bf16(a[rt], b[ct], acc[rt][ct], 0, 0, 0);
    }
    __syncthreads();

    // epilogue 2 -> lx (gelu, bf16)
#pragma unroll
    for (int ct = 0; ct < 4; ++ct) {
        int col = wc * 64 + ct * 16 + l16;
        float bias = b2[col];
#pragma unroll
        for (int rt = 0; rt < 4; ++rt)
#pragma unroll
            for (int r = 0; r < 4; ++r)
                lx[wr * 64 + rt * 16 + quad * 4 + r][col] = (bf16)gelu_f(acc[rt][ct][r] + bias);
    }
    __syncthreads();

    // ---- layer 3: K = 128 ----
#pragma unroll
    for (int i = 0; i < 4; ++i)
#pragma unroll
        for (int j = 0; j < 4; ++j) acc[i][j] = (f32x4){0.f, 0.f, 0.f, 0.f};
#pragma unroll
    for (int ks = 0; ks < 4; ++ks) {
        bf16x8 a[4], b[4];
#pragma unroll
        for (int rt = 0; rt < 4; ++rt)
            a[rt] = *(const bf16x8*)&lx[wr * 64 + rt * 16 + l16][ks * 32 + quad * 8];
#pragma unroll
        for (int ct = 0; ct < 4; ++ct)
            b[ct] = *(const bf16x8*)(W3b + (size_t)(wc * 64 + ct * 16 + l16) * HD + ks * 32 + quad * 8);
#pragma unroll
        for (int rt = 0; rt < 4; ++rt)
#pragma unroll
            for (int ct = 0; ct < 4; ++ct)
                acc[rt][ct] = __builtin_amdgcn_mfma_f32_16x16x32_bf16(a[rt], b[ct], acc[rt][ct], 0, 0, 0);
    }

    // epilogue 3: z = acc + b3, in two 64-col halves through lz; segmented reduce.
    float b3c[4];
#pragma unroll
    for (int ct = 0; ct < 4; ++ct) b3c[ct] = b3[wc * 64 + ct * 16 + l16];

#pragma unroll
    for (int half = 0; half < 2; ++half) {
        __syncthreads();     // lx reads (layer 3 / prior half) complete before overwrite
        if (wc == half) {
#pragma unroll
            for (int ct = 0; ct < 4; ++ct)
#pragma unroll
                for (int rt = 0; rt < 4; ++rt)
#pragma unroll
                    for (int r = 0; r < 4; ++r)
                        lz[wr * 64 + rt * 16 + quad * 4 + r][ct * 16 + l16] =
                            acc[rt][ct][r] + b3c[ct];
        }
        __syncthreads();
        // sorted src -> contiguous runs. thread: col=tid&63, rows [h*32, h*32+32).
        const int c = tid & 63, h = tid >> 6;
        const int rbeg = h * 32, rend = rbeg + 32;
        float sum = lz[rbeg][c];
        int cur = ssrc[rbeg];
        for (int r = rbeg + 1; r < rend; ++r) {
            int s = ssrc[r];
            float v = lz[r][c];
            if (s != cur) {
                atomicAdd(segsum + (size_t)cur * HD + half * 64 + c, sum);
                cur = s; sum = v;
            } else {
                sum += v;
            }
        }
        atomicAdd(segsum + (size_t)cur * HD + half * 64 + c, sum);
    }
}

// ---- node: dh + residual + LN1 -> FFN -> residual + LN2 ----
__global__ __launch_bounds__(256, 2) void node_ffn(
    const float* __restrict__ hV, float* __restrict__ out /* segsum in, h_V out */,
    const int* __restrict__ cnt,
    const bf16* __restrict__ Winb, const bf16* __restrict__ Woutb,
    const float* __restrict__ bin, const float* __restrict__ bout,
    const float* __restrict__ g1, const float* __restrict__ be1,
    const float* __restrict__ g2, const float* __restrict__ be2)
{
    __shared__ bf16 lx[128][136];
    __shared__ bf16 ly[128][72];
    __shared__ float ps[128][2], pq[128][2];
    const int tid  = threadIdx.x;
    const int wave = tid >> 6, lane = tid & 63;
    const int wr = wave >> 1, wc = wave & 1;
    const int quad = lane >> 4, l16 = lane & 15;
    const int base = blockIdx.x * 128;

    // phase 1: 4 threads/row, bulk-parallel loads. u = hV + seg/max(cnt,1)/30; LN1 -> lx.
#pragma unroll
    for (int p = 0; p < 2; ++p) {
        const int rl = p * 64 + (tid >> 2);
        const int qf = tid & 3;
        const int node = base + rl;
        const bool valid = node < NN;
        float u[32];
        float sm = 0.f, sq = 0.f;
        if (valid) {
            int c = cnt[node];
            float inv = 1.0f / (30.0f * (float)(c > 1 ? c : 1));
            const float* ph = hV  + (size_t)node * HD + qf * 32;
            const float* pz = out + (size_t)node * HD + qf * 32;
#pragma unroll
            for (int i = 0; i < 8; ++i) {
                f32x4 a = *(const f32x4*)(ph + 4 * i);
                f32x4 s = *(const f32x4*)(pz + 4 * i);
#pragma unroll
                for (int j = 0; j < 4; ++j) {
                    float uu = a[j] + s[j] * inv;
                    u[4 * i + j] = uu; sm += uu; sq += uu * uu;
                }
            }
        } else {
#pragma unroll
            for (int i = 0; i < 32; ++i) u[i] = 0.f;
        }
        sm += __shfl_xor(sm, 1, 64); sq += __shfl_xor(sq, 1, 64);
        sm += __shfl_xor(sm, 2, 64); sq += __shfl_xor(sq, 2, 64);
        float mean = sm * (1.0f / 128.0f);
        float var  = sq * (1.0f / 128.0f) - mean * mean;
        float rstd = rsqrtf(var + 1e-5f);
#pragma unroll
        for (int i = 0; i < 4; ++i) {
            bf16x8 w;
#pragma unroll
            for (int j = 0; j < 8; ++j) {
                int col = qf * 32 + i * 8 + j;
                float x = valid ? ((u[i * 8 + j] - mean) * rstd * g1[col] + be1[col]) : 0.f;
                w[j] = (bf16)x;
            }
            *(bf16x8*)&lx[rl][qf * 32 + i * 8] = w;
        }
    }
    __syncthreads();

    f32x4 oacc[4][4];
#pragma unroll
    for (int i = 0; i < 4; ++i)
#pragma unroll
        for (int j = 0; j < 4; ++j) oacc[i][j] = (f32x4){0.f, 0.f, 0.f, 0.f};

    for (int c = 0; c < 8; ++c) {   // FF=512 in 8 chunks of 64
        f32x4 a1[4][2];
#pragma unroll
        for (int i = 0; i < 4; ++i)
#pragma unroll
            for (int j = 0; j < 2; ++j) a1[i][j] = (f32x4){0.f, 0.f, 0.f, 0.f};
#pragma unroll
        for (int ks = 0; ks < 4; ++ks) {
            bf16x8 a[4], b[2];
#pragma unroll
            for (int rt = 0; rt < 4; ++rt)
                a[rt] = *(const bf16x8*)&lx[wr * 64 + rt * 16 + l16][ks * 32 + quad * 8];
#pragma unroll
            for (int ct = 0; ct < 2; ++ct) {
                int f = c * 64 + wc * 32 + ct * 16 + l16;
                b[ct] = *(const bf16x8*)(Winb + (size_t)f * HD + ks * 32 + quad * 8);
            }
#pragma unroll
            for (int rt = 0; rt < 4; ++rt)
#pragma unroll
                for (int ct = 0; ct < 2; ++ct)
                    a1[rt][ct] = __builtin_amdgcn_mfma_f32_16x16x32_bf16(a[rt], b[ct], a1[rt][ct], 0, 0, 0);
        }
        __syncthreads();
#pragma unroll
        for (int ct = 0; ct < 2; ++ct) {
            int f  = c * 64 + wc * 32 + ct * 16 + l16;
            int fl = wc * 32 + ct * 16 + l16;
            float bias = bin[f];
#pragma unroll
            for (int rt = 0; rt < 4; ++rt)
#pragma unroll
                for (int r = 0; r < 4; ++r)
                    ly[wr * 64 + rt * 16 + quad * 4 + r][fl] = (bf16)gelu_f(a1[rt][ct][r] + bias);
        }
        __syncthreads();
#pragma unroll
        for (int ks = 0; ks < 2; ++ks) {
            bf16x8 a[4], b[4];
#pragma unroll
            for (int rt = 0; rt < 4; ++rt)
                a[rt] = *(const bf16x8*)&ly[wr * 64 + rt * 16 + l16][ks * 32 + quad * 8];
#pragma unroll
            for (int ct = 0; ct < 4; ++ct) {
                int o = wc * 64 + ct * 16 + l16;
                b[ct] = *(const bf16x8*)(Woutb + (size_t)o * FFD + c * 64 + ks * 32 + quad * 8);
            }
#pragma unroll
            for (int rt = 0; rt < 4; ++rt)
#pragma unroll
                for (int ct = 0; ct < 4; ++ct)
                    oacc[rt][ct] = __builtin_amdgcn_mfma_f32_16x16x32_bf16(a[rt], b[ct], oacc[rt][ct], 0, 0, 0);
        }
    }

    // z = ffn + b_out + x; LN2 row stats via quad butterfly + LDS combine
    float bo[4];
#pragma unroll
    for (int ct = 0; ct < 4; ++ct) bo[ct] = bout[wc * 64 + ct * 16 + l16];
#pragma unroll
    for (int rt = 0; rt < 4; ++rt)
#pragma unroll
        for (int r = 0; r < 4; ++r) {
            int rl = wr * 64 + rt * 16 + quad * 4 + r;
            float sm = 0.f, sq = 0.f;
#pragma unroll
            for (int ct = 0; ct < 4; ++ct) {
                int o = wc * 64 + ct * 16 + l16;
                float zz = oacc[rt][ct][r] + bo[ct] + (float)lx[rl][o];
                oacc[rt][ct][r] = zz;
                sm += zz; sq += zz * zz;
            }
#pragma unroll
            for (int m = 1; m < 16; m <<= 1) {
                sm += __shfl_xor(sm, m, 64);
                sq += __shfl_xor(sq, m, 64);
            }
            if (l16 == 0) { ps[rl][wc] = sm; pq[rl][wc] = sq; }
        }
    __syncthreads();
#pragma unroll
    for (int rt = 0; rt < 4; ++rt)
#pragma unroll
        for (int r = 0; r < 4; ++r) {
            int rl = wr * 64 + rt * 16 + quad * 4 + r;
            int node = base + rl;
            float S = ps[rl][0] + ps[rl][1];
            float Q = pq[rl][0] + pq[rl][1];
            float mean = S * (1.0f / 128.0f);
            float var  = Q * (1.0f / 128.0f) - mean * mean;
            float rstd = rsqrtf(var + 1e-5f);
            if (node < NN) {
#pragma unroll
                for (int ct = 0; ct < 4; ++ct) {
                    int o = wc * 64 + ct * 16 + l16;
                    out[(size_t)node * HD + o] = (oacc[rt][ct][r] - mean) * rstd * g2[o] + be2[o];
                }
            }
        }
}

extern "C" void kernel_launch(void* const* d_in, const int* in_sizes, int n_in,
                              void* d_out, int out_size, void* d_ws, size_t ws_size,
                              hipStream_t stream) {
    const float* hV   = (const float*)d_in[0];
    const float* hE   = (const float*)d_in[1];
    const int*   src  = (const int*)d_in[2];
    const int*   dst  = (const int*)d_in[4];
    const float* W1   = (const float*)d_in[5];
    const float* b1   = (const float*)d_in[6];
    const float* W2   = (const float*)d_in[7];
    const float* b2   = (const float*)d_in[8];
    const float* W3   = (const float*)d_in[9];
    const float* b3   = (const float*)d_in[10];
    const float* g1   = (const float*)d_in[11];
    const float* be1  = (const float*)d_in[12];
    const float* g2   = (const float*)d_in[13];
    const float* be2  = (const float*)d_in[14];
    const float* Win  = (const float*)d_in[15];
    const float* bin  = (const float*)d_in[16];
    const float* Wout = (const float*)d_in[17];
    const float* bout = (const float*)d_in[18];

    float* out = (float*)d_out;
    // ws layout (bytes): wbf 0..425984, cnt @425984, head @625984, perm @825984,
    //                    bsum @4025984 (196 ints)
    bf16* wbf  = (bf16*)d_ws;
    int*  cnt  = (int*)((char*)d_ws + 425984);
    int*  head = (int*)((char*)d_ws + 625984);
    int*  perm = (int*)((char*)d_ws + 825984);
    int*  bsum = (int*)((char*)d_ws + 4025984);

    const int NB = (NN + 255) / 256;   // 196

    hipMemsetAsync(d_out, 0, (size_t)NN * HD * sizeof(float), stream);
    hipMemsetAsync(cnt, 0, NN * sizeof(int), stream);

    cvt_weights<<<832, 256, 0, stream>>>(W1, W2, W3, Win, Wout, wbf);
    hist_kernel<<<(NE + 255) / 256, 256, 0, stream>>>(src, cnt);
    scan_a<<<NB, 256, 0, stream>>>(cnt, head, bsum);
    scan_b<<<1, 256, 0, stream>>>(bsum, NB);
    scan_c<<<NB, 256, 0, stream>>>(head, bsum);
    scatter_perm<<<(NE + 255) / 256, 256, 0, stream>>>(src, head, perm);
    edge_mlp<<<NE / 128, 256, 0, stream>>>(hV, hE, src, dst, perm,
                                           wbf, wbf + 49152, wbf + 65536,
                                           b1, b2, b3, out);
    node_ffn<<<(NN + 127) / 128, 256, 0, stream>>>(hV, out, cnt,
                                                   wbf + 81920, wbf + 147456,
                                                   bin, bout, g1, be1, g2, be2);
}